// Round 1
// baseline (104.474 us; speedup 1.0000x reference)
//
#include <hip/hip_runtime.h>

// SPN forward: gate-normalize + horizontal left->right 2D gated scan.
// [B=8, C=32, H=256, W=256] fp32. One 256-thread block per (b,c) plane,
// thread i owns row i. 16-column stages: coalesced float4 row loads ->
// normalize in regs -> transposed packed LDS tile -> per-step scan with
// LDS halo'd double-buffered h exchange (1 barrier/step).

#define HD 256
#define WD 256
#define TW 16
#define NST (WD / TW)   // 16 stages

__global__ __launch_bounds__(256) void spn_fwd(
    const float* __restrict__ x, const float* __restrict__ G1,
    const float* __restrict__ G2, const float* __restrict__ G3,
    float* __restrict__ out)
{
    // [col][row] packed {x, g1, g2, g3}: 16*256*16B = 64 KiB
    __shared__ float4 sf[TW * HD];
    // halo'd double-buffered h: h for previous column lives here
    __shared__ float sh[2][HD + 2];

    const int i = threadIdx.x;                      // row
    const size_t base = (size_t)blockIdx.x * (HD * WD) + (size_t)i * WD;
    const float* xr = x  + base;
    const float* ar = G1 + base;
    const float* br = G2 + base;
    const float* cr = G3 + base;
    float* orow = out + base;

    const float upOk = (i > 0) ? 1.f : 0.f;         // g1 needs row i-1
    const float dnOk = (i < HD - 1) ? 1.f : 0.f;    // g3 needs row i+1

    float4 px[4], pa[4], pb[4], pc[4];              // prefetch regs (one row x 16 cols)

    // ---- prefetch stage 0 (coalesced: 64B contiguous per thread)
    {
        const float4* x4 = (const float4*)(xr);
        const float4* a4 = (const float4*)(ar);
        const float4* b4 = (const float4*)(br);
        const float4* c4 = (const float4*)(cr);
#pragma unroll
        for (int k = 0; k < 4; ++k) {
            px[k] = x4[k]; pa[k] = a4[k]; pb[k] = b4[k]; pc[k] = c4[k];
        }
    }

    // zero-init h buffers incl. halos (avoid NaN*0 from uninitialized LDS)
    sh[0][i + 1] = 0.f;
    sh[1][i + 1] = 0.f;
    if (i < 2) { sh[i][0] = 0.f; sh[i][HD + 1] = 0.f; }

    // ---- normalize + boundary-mask + write transposed packed tile to LDS
    auto stage_write = [&](int j0) {
#pragma unroll
        for (int k = 0; k < 4; ++k) {
            float X[4]  = {px[k].x, px[k].y, px[k].z, px[k].w};
            float A[4]  = {pa[k].x, pa[k].y, pa[k].z, pa[k].w};
            float Bv[4] = {pb[k].x, pb[k].y, pb[k].z, pb[k].w};
            float Cv[4] = {pc[k].x, pc[k].y, pc[k].z, pc[k].w};
#pragma unroll
            for (int e = 0; e < 4; ++e) {
                float a = A[e], b = Bv[e], c = Cv[e];
                float s = fabsf(a) + fabsf(b) + fabsf(c);
                // where s>=1: divide by s (s==0 -> keep branch, matches ref)
                float inv = (s >= 1.f) ? (1.f / s) : 1.f;
                a *= inv; b *= inv; c *= inv;
                float cm = (j0 + k * 4 + e > 0) ? 1.f : 0.f;   // no left neighbor at j=0
                a *= cm * upOk;
                b *= cm;
                c *= cm * dnOk;
                sf[(k * 4 + e) * HD + i] = make_float4(X[e], a, b, c);
            }
        }
    };

    stage_write(0);
    __syncthreads();

    float hprev = 0.f;   // h[i, j-1]
#pragma unroll 1
    for (int t = 0; t < NST; ++t) {
        const int j0 = t * TW;

        // prefetch next stage while scanning this one
        if (t + 1 < NST) {
            const float4* x4 = (const float4*)(xr + j0 + TW);
            const float4* a4 = (const float4*)(ar + j0 + TW);
            const float4* b4 = (const float4*)(br + j0 + TW);
            const float4* c4 = (const float4*)(cr + j0 + TW);
#pragma unroll
            for (int k = 0; k < 4; ++k) {
                px[k] = x4[k]; pa[k] = a4[k]; pb[k] = b4[k]; pc[k] = c4[k];
            }
        }

        // ---- scan 16 columns; h exchange via double-buffered halo'd LDS
        float o[TW];
#pragma unroll
        for (int jj = 0; jj < TW; ++jj) {
            const int rb = jj & 1;                      // read buffer (compile-time)
            float4 v = sf[jj * HD + i];                 // {x, g1, g2, g3}
            float up = sh[rb][i];                       // h[i-1, j-1] (halo=0 at i=0)
            float dn = sh[rb][i + 2];                   // h[i+1, j-1]
            float h = (1.f - v.y - v.z - v.w) * v.x
                    + v.y * up + v.z * hprev + v.w * dn;
            sh[rb ^ 1][i + 1] = h;
            __syncthreads();
            hprev = h;
            o[jj] = h;
        }

        // ---- coalesced row store (64B contiguous per thread)
        float4* o4 = (float4*)(orow + j0);
#pragma unroll
        for (int k = 0; k < 4; ++k)
            o4[k] = make_float4(o[4 * k], o[4 * k + 1], o[4 * k + 2], o[4 * k + 3]);

        if (t + 1 < NST) {
            stage_write(j0 + TW);   // waits on prefetch loads (compiler vmcnt)
            __syncthreads();
        }
    }
}

extern "C" void kernel_launch(void* const* d_in, const int* in_sizes, int n_in,
                              void* d_out, int out_size, void* d_ws, size_t ws_size,
                              hipStream_t stream) {
    const float* x  = (const float*)d_in[0];
    const float* g1 = (const float*)d_in[1];
    const float* g2 = (const float*)d_in[2];
    const float* g3 = (const float*)d_in[3];
    float* out = (float*)d_out;
    const int planes = out_size / (HD * WD);   // B*C = 256
    spn_fwd<<<planes, 256, 0, stream>>>(x, g1, g2, g3, out);
}